// Round 18
// baseline (142.842 us; speedup 1.0000x reference)
//
#include <hip/hip_runtime.h>
#include <math.h>

#define IND   64
#define OUTD  101
#define RPB   64
#define NCT   7              // 7 col-tiles x 16 = 112 padded cols
#define LROW  101            // LDS row stride (words)
#define QTR_WORDS (16 * OUTD)    // 1616 words = 6464 B per 16-row quarter

typedef _Float16 half8 __attribute__((ext_vector_type(8)));
typedef float    f32x4 __attribute__((ext_vector_type(4)));

// Ladder: R15 LDS-staged linear drain (170->149), R16 finer quarters + 16
// blocks/CU (->144.5), R17 nontemporal drain stores (->129.2).
// R18 single change: NON-PERSISTENT grid -- 15625 blocks, one 64-row tile
// each. Kills the 4.8% round-quantization of the persistent 4096-block grid
// (3337 blocks x4 tiles / 759 x3 -> 4-round makespan); the HW dispatcher
// backfills continuously. W prologue is L2-hot (every block reads the same
// 26KB), costing ~1-2% -- net win expected.
__global__ __launch_bounds__(64, 3) void density_kernel(
    const float* __restrict__ t,
    const float* __restrict__ x,
    const float* __restrict__ weight,
    const float* __restrict__ bias,
    const int*   __restrict__ num_grid,
    float* __restrict__ out1,
    float* __restrict__ out_interp,
    int n_rows)
{
    __shared__ float ptile[QTR_WORDS];   // 6464 B, reused for all 4 quarters

    const int lane = threadIdx.x;
    const int lc   = lane & 15;        // col-in-tile (R5 mapping)
    const int lg   = lane >> 4;        // k-group / row-group
    const float ngf = (float)num_grid[0];
    const int tile = blockIdx.x;
    const int row0 = tile * RPB;

    // ---- W fragments + bias ----
    half8 wf[NCT][2];
    float biasv[NCT];
#pragma unroll
    for (int ct = 0; ct < NCT; ++ct) {
        const int col  = ct * 16 + lc;
        const int colc = (col < OUTD) ? col : (OUTD - 1);
        biasv[ct] = (col < OUTD) ? bias[col] : -1e30f;   // pads killed via bias
#pragma unroll
        for (int kg = 0; kg < 2; ++kg) {
            half8 h;
#pragma unroll
            for (int j = 0; j < 8; ++j)
                h[j] = (_Float16)weight[(kg * 32 + lg * 8 + j) * OUTD + colc];
            wf[ct][kg] = h;
        }
    }

    #define XPTR(RT) \
        ((const f32x4*)(x + (size_t)min(row0 + (RT) * 16 + lc, n_rows - 1) * IND + lg * 8))

    // ---- 2-buffer ping-pong x prefetch (static register names, rule #20) ----
    f32x4 pa0, pa1, pa2, pa3, pb0, pb1, pb2, pb3;
    {   // prime: rt=0 -> A buffer
        const f32x4* p = XPTR(0);
        pa0 = p[0]; pa1 = p[1]; pa2 = p[8]; pa3 = p[9];
    }

    // shared body: MFMA + softmax + LDS quarter write from CUR regs
    #define BODY(C0, C1, C2, C3)                                                 \
        half8 a0, a1;                                                            \
        _Pragma("unroll")                                                        \
        for (int i = 0; i < 4; ++i) {                                            \
            a0[i] = (_Float16)C0[i]; a0[4 + i] = (_Float16)C1[i];                \
            a1[i] = (_Float16)C2[i]; a1[4 + i] = (_Float16)C3[i];                \
        }                                                                        \
        f32x4 c[NCT];                                                            \
        _Pragma("unroll")                                                        \
        for (int ct = 0; ct < NCT; ++ct) {                                       \
            f32x4 ci = {biasv[ct], biasv[ct], biasv[ct], biasv[ct]};             \
            ci = __builtin_amdgcn_mfma_f32_16x16x32_f16(a0, wf[ct][0], ci,0,0,0);\
            ci = __builtin_amdgcn_mfma_f32_16x16x32_f16(a1, wf[ct][1], ci,0,0,0);\
            c[ct] = ci;                                                          \
        }                                                                        \
        float m[4], s[4];                                                        \
        _Pragma("unroll")                                                        \
        for (int j = 0; j < 4; ++j) {                                            \
            float mj = c[0][j];                                                  \
            _Pragma("unroll")                                                    \
            for (int ct = 1; ct < NCT; ++ct) mj = fmaxf(mj, c[ct][j]);           \
            _Pragma("unroll")                                                    \
            for (int d = 1; d < 16; d <<= 1) mj = fmaxf(mj, __shfl_xor(mj,d,64));\
            m[j] = mj; s[j] = 0.0f;                                              \
        }                                                                        \
        _Pragma("unroll")                                                        \
        for (int ct = 0; ct < NCT; ++ct)                                         \
            _Pragma("unroll")                                                    \
            for (int j = 0; j < 4; ++j) {                                        \
                const float e = __expf(c[ct][j] - m[j]);                         \
                c[ct][j] = e; s[j] += e;                                         \
            }                                                                    \
        _Pragma("unroll")                                                        \
        for (int j = 0; j < 4; ++j) {                                            \
            _Pragma("unroll")                                                    \
            for (int d = 1; d < 16; d <<= 1) s[j] += __shfl_xor(s[j], d, 64);    \
            float inv = __builtin_amdgcn_rcpf(s[j]);                             \
            inv = inv * (2.0f - s[j] * inv);                                     \
            s[j] = inv;                                                          \
        }                                                                        \
        _Pragma("unroll")                                                        \
        for (int ct = 0; ct < NCT; ++ct) {                                       \
            const int col = ct * 16 + lc;                                        \
            if (col < OUTD) {                                                    \
                _Pragma("unroll")                                                \
                for (int j = 0; j < 4; ++j)                                      \
                    ptile[(lg * 4 + j) * LROW + col] = c[ct][j] * s[j];          \
            }                                                                    \
        }

    // consume CUR regs, prefetch rt=PR into NXT regs
    #define PROCESS(C0, C1, C2, C3, N0, N1, N2, N3, PR)                          \
    {                                                                            \
        {   const f32x4* np = XPTR(PR);                                          \
            N0 = np[0]; N1 = np[1]; N2 = np[8]; N3 = np[9]; }                    \
        BODY(C0, C1, C2, C3)                                                     \
    }
    // last quarter: no prefetch
    #define PROCESS_NOPF(C0, C1, C2, C3)                                         \
    {                                                                            \
        BODY(C0, C1, C2, C3)                                                     \
    }

    // drain one 16-row quarter: 6464B contiguous, 16B-aligned, nt dwordx4
    #define DRAIN(Q)                                                             \
    {                                                                            \
        float* obase = out1 + (size_t)tile * (RPB * OUTD) + (Q) * QTR_WORDS;     \
        if (row0 + RPB <= n_rows) {                                              \
            _Pragma("unroll")                                                    \
            for (int i = 0; i < 6; ++i) {                                        \
                const f32x4 v = *(const f32x4*)&ptile[i * 256 + lane * 4];       \
                __builtin_nontemporal_store(v, (f32x4*)(obase + i * 256 + lane * 4)); \
            }                                                                    \
            if (lane < 20) {                                                     \
                const f32x4 v = *(const f32x4*)&ptile[1536 + lane * 4];          \
                __builtin_nontemporal_store(v, (f32x4*)(obase + 1536 + lane * 4)); \
            }                                                                    \
        } else {  /* partial tile (never hit at N=1e6): guarded scalar */        \
            for (int r = 0; r < 16; ++r) {                                       \
                const int grr = row0 + (Q) * 16 + r;                             \
                if (grr < n_rows)                                                \
                    for (int cc = lane; cc < OUTD; cc += 64)                     \
                        out1[(size_t)grr * OUTD + cc] = ptile[r * LROW + cc];    \
            }                                                                    \
        }                                                                        \
        /* interp from own LDS row: quarter Q owns lanes Q*16..Q*16+15 */        \
        if ((lane >> 4) == (Q) && gr < n_rows) {                                 \
            const float Lv = ptile[(lane & 15) * LROW + Li];                     \
            const float Uv = ptile[(lane & 15) * LROW + Ui];                     \
            out_interp[gr] = Lv + (Uv - Lv) * inter;                             \
        }                                                                        \
    }

    // own-row interp indices, kept in registers (lane owns row row0+lane)
    const int gr  = row0 + lane;
    const int grc = (gr < n_rows) ? gr : (n_rows - 1);
    const float tB = t[grc] * ngf;
    const float Uf = ceilf(tB);
    const float inter = 1.0f - (Uf - tB);
    float Lf = Uf - 1.0f;
    if (Lf < 0.0f) Lf += 1.0f;
    const int Li = (int)Lf, Ui = (int)Uf;

    PROCESS(pa0, pa1, pa2, pa3, pb0, pb1, pb2, pb3, 1)
    DRAIN(0)
    PROCESS(pb0, pb1, pb2, pb3, pa0, pa1, pa2, pa3, 2)
    DRAIN(1)
    PROCESS(pa0, pa1, pa2, pa3, pb0, pb1, pb2, pb3, 3)
    DRAIN(2)
    PROCESS_NOPF(pb0, pb1, pb2, pb3)
    DRAIN(3)

    #undef DRAIN
    #undef PROCESS
    #undef PROCESS_NOPF
    #undef BODY
    #undef XPTR
}

extern "C" void kernel_launch(void* const* d_in, const int* in_sizes, int n_in,
                              void* d_out, int out_size, void* d_ws, size_t ws_size,
                              hipStream_t stream) {
    const float* t  = (const float*)d_in[0];
    const float* x  = (const float*)d_in[1];
    const float* w  = (const float*)d_in[2];
    const float* b  = (const float*)d_in[3];
    const int*   ng = (const int*)d_in[4];
    const int n_rows = in_sizes[0];

    float* out1       = (float*)d_out;
    float* out_interp = out1 + (size_t)n_rows * OUTD;

    // non-persistent: one 64-row tile per block; HW dispatcher backfills,
    // eliminating the persistent grid's 4.8% round-quantization tail.
    const int n_blocks = (n_rows + RPB - 1) / RPB;   // 15625
    density_kernel<<<dim3(n_blocks), dim3(64), 0, stream>>>(
        t, x, w, b, ng, out1, out_interp, n_rows);
}

// Round 19
// 126.941 us; speedup vs baseline: 1.1253x; 1.1253x over previous
//
#include <hip/hip_runtime.h>
#include <math.h>

#define IND   64
#define OUTD  101
#define RPB   64
#define NCT   7              // 7 col-tiles x 16 = 112 padded cols
#define LROW  101            // LDS row stride (words)
#define QTR_WORDS (16 * OUTD)    // 1616 words = 6464 B per 16-row quarter

typedef _Float16 half8 __attribute__((ext_vector_type(8)));
typedef float    f32x4 __attribute__((ext_vector_type(4)));

// R17 configuration (best: 129.2us) -- exact revert of the R18 experiment.
// Ladder: R15 LDS-staged linear drain (170->149), R16 finer quarters + 16
// blocks/CU (->144.5), R17 nontemporal drain stores (->129.2), R18
// non-persistent grid (->142.8, REGRESSION: per-block W prologue ~410MB
// aggregate L2 + launch overhead; per-CU balance at 4096 was already 1.6%).
__global__ __launch_bounds__(64, 3) void density_kernel(
    const float* __restrict__ t,
    const float* __restrict__ x,
    const float* __restrict__ weight,
    const float* __restrict__ bias,
    const int*   __restrict__ num_grid,
    float* __restrict__ out1,
    float* __restrict__ out_interp,
    int n_rows, int n_tiles, int n_blocks)
{
    __shared__ float ptile[QTR_WORDS];   // 6464 B, reused for all 4 quarters

    const int lane = threadIdx.x;
    const int lc   = lane & 15;        // col-in-tile (R5 mapping)
    const int lg   = lane >> 4;        // k-group / row-group
    const float ngf = (float)num_grid[0];

    // ---- W fragments + bias ----
    half8 wf[NCT][2];
    float biasv[NCT];
#pragma unroll
    for (int ct = 0; ct < NCT; ++ct) {
        const int col  = ct * 16 + lc;
        const int colc = (col < OUTD) ? col : (OUTD - 1);
        biasv[ct] = (col < OUTD) ? bias[col] : -1e30f;   // pads killed via bias
#pragma unroll
        for (int kg = 0; kg < 2; ++kg) {
            half8 h;
#pragma unroll
            for (int j = 0; j < 8; ++j)
                h[j] = (_Float16)weight[(kg * 32 + lg * 8 + j) * OUTD + colc];
            wf[ct][kg] = h;
        }
    }

    #define XPTR(TILE, RT) \
        ((const f32x4*)(x + (size_t)min((TILE) * RPB + (RT) * 16 + lc, n_rows - 1) * IND + lg * 8))

    // ---- 2-buffer ping-pong x prefetch (static register names, rule #20) ----
    f32x4 pa0, pa1, pa2, pa3, pb0, pb1, pb2, pb3;

    int tile = blockIdx.x;
    {   // prime: tile rt=0 -> A buffer
        const f32x4* p = XPTR(tile, 0);
        pa0 = p[0]; pa1 = p[1]; pa2 = p[8]; pa3 = p[9];
    }

    // one row-tile: consume CUR regs, prefetch (PT,PR) into NXT regs,
    // write normalized probs into the 16-row LDS quarter (rows lg*4+j)
    #define PROCESS(RT, C0, C1, C2, C3, N0, N1, N2, N3, PT, PR)                  \
    {                                                                            \
        {   const f32x4* np = XPTR(PT, PR);                                      \
            N0 = np[0]; N1 = np[1]; N2 = np[8]; N3 = np[9]; }                    \
        half8 a0, a1;                                                            \
        _Pragma("unroll")                                                        \
        for (int i = 0; i < 4; ++i) {                                            \
            a0[i] = (_Float16)C0[i]; a0[4 + i] = (_Float16)C1[i];                \
            a1[i] = (_Float16)C2[i]; a1[4 + i] = (_Float16)C3[i];                \
        }                                                                        \
        f32x4 c[NCT];                                                            \
        _Pragma("unroll")                                                        \
        for (int ct = 0; ct < NCT; ++ct) {                                       \
            f32x4 ci = {biasv[ct], biasv[ct], biasv[ct], biasv[ct]};             \
            ci = __builtin_amdgcn_mfma_f32_16x16x32_f16(a0, wf[ct][0], ci,0,0,0);\
            ci = __builtin_amdgcn_mfma_f32_16x16x32_f16(a1, wf[ct][1], ci,0,0,0);\
            c[ct] = ci;                                                          \
        }                                                                        \
        float m[4], s[4];                                                        \
        _Pragma("unroll")                                                        \
        for (int j = 0; j < 4; ++j) {                                            \
            float mj = c[0][j];                                                  \
            _Pragma("unroll")                                                    \
            for (int ct = 1; ct < NCT; ++ct) mj = fmaxf(mj, c[ct][j]);           \
            _Pragma("unroll")                                                    \
            for (int d = 1; d < 16; d <<= 1) mj = fmaxf(mj, __shfl_xor(mj,d,64));\
            m[j] = mj; s[j] = 0.0f;                                              \
        }                                                                        \
        _Pragma("unroll")                                                        \
        for (int ct = 0; ct < NCT; ++ct)                                         \
            _Pragma("unroll")                                                    \
            for (int j = 0; j < 4; ++j) {                                        \
                const float e = __expf(c[ct][j] - m[j]);                         \
                c[ct][j] = e; s[j] += e;                                         \
            }                                                                    \
        _Pragma("unroll")                                                        \
        for (int j = 0; j < 4; ++j) {                                            \
            _Pragma("unroll")                                                    \
            for (int d = 1; d < 16; d <<= 1) s[j] += __shfl_xor(s[j], d, 64);    \
            float inv = __builtin_amdgcn_rcpf(s[j]);                             \
            inv = inv * (2.0f - s[j] * inv);                                     \
            s[j] = inv;                                                          \
        }                                                                        \
        _Pragma("unroll")                                                        \
        for (int ct = 0; ct < NCT; ++ct) {                                       \
            const int col = ct * 16 + lc;                                        \
            if (col < OUTD) {                                                    \
                _Pragma("unroll")                                                \
                for (int j = 0; j < 4; ++j)                                      \
                    ptile[(lg * 4 + j) * LROW + col] = c[ct][j] * s[j];          \
            }                                                                    \
        }                                                                        \
    }

    // drain one 16-row quarter: 6464B contiguous, 16B-aligned, nt dwordx4
    #define DRAIN(Q)                                                             \
    {                                                                            \
        float* obase = out1 + (size_t)tile * (RPB * OUTD) + (Q) * QTR_WORDS;     \
        if (row0 + RPB <= n_rows) {                                              \
            _Pragma("unroll")                                                    \
            for (int i = 0; i < 6; ++i) {                                        \
                const f32x4 v = *(const f32x4*)&ptile[i * 256 + lane * 4];       \
                __builtin_nontemporal_store(v, (f32x4*)(obase + i * 256 + lane * 4)); \
            }                                                                    \
            if (lane < 20) {                                                     \
                const f32x4 v = *(const f32x4*)&ptile[1536 + lane * 4];          \
                __builtin_nontemporal_store(v, (f32x4*)(obase + 1536 + lane * 4)); \
            }                                                                    \
        } else {  /* partial tile (never hit at N=1e6): guarded scalar */        \
            for (int r = 0; r < 16; ++r) {                                       \
                const int grr = row0 + (Q) * 16 + r;                             \
                if (grr < n_rows)                                                \
                    for (int cc = lane; cc < OUTD; cc += 64)                     \
                        out1[(size_t)grr * OUTD + cc] = ptile[r * LROW + cc];    \
            }                                                                    \
        }                                                                        \
        /* interp from own LDS row: quarter Q owns lanes Q*16..Q*16+15 */        \
        if ((lane >> 4) == (Q) && gr < n_rows) {                                 \
            const float Lv = ptile[(lane & 15) * LROW + Li];                     \
            const float Uv = ptile[(lane & 15) * LROW + Ui];                     \
            out_interp[gr] = Lv + (Uv - Lv) * inter;                             \
        }                                                                        \
    }

    for (; tile < n_tiles; tile += n_blocks) {
        const int row0 = tile * RPB;

        // own-row interp indices, kept in registers (lane owns row row0+lane)
        const int gr  = row0 + lane;
        const int grc = (gr < n_rows) ? gr : (n_rows - 1);
        const float tB = t[grc] * ngf;
        const float Uf = ceilf(tB);
        const float inter = 1.0f - (Uf - tB);
        float Lf = Uf - 1.0f;
        if (Lf < 0.0f) Lf += 1.0f;
        const int Li = (int)Lf, Ui = (int)Uf;

        const int  ntile = tile + n_blocks;
        const int  pt    = (ntile < n_tiles) ? ntile : tile;   // clamp: dummy reload

        PROCESS(0, pa0, pa1, pa2, pa3, pb0, pb1, pb2, pb3, tile, 1)
        DRAIN(0)
        PROCESS(1, pb0, pb1, pb2, pb3, pa0, pa1, pa2, pa3, tile, 2)
        DRAIN(1)
        PROCESS(2, pa0, pa1, pa2, pa3, pb0, pb1, pb2, pb3, tile, 3)
        DRAIN(2)
        PROCESS(3, pb0, pb1, pb2, pb3, pa0, pa1, pa2, pa3, pt,   0)
        DRAIN(3)
    }
    #undef DRAIN
    #undef PROCESS
    #undef XPTR
}

extern "C" void kernel_launch(void* const* d_in, const int* in_sizes, int n_in,
                              void* d_out, int out_size, void* d_ws, size_t ws_size,
                              hipStream_t stream) {
    const float* t  = (const float*)d_in[0];
    const float* x  = (const float*)d_in[1];
    const float* w  = (const float*)d_in[2];
    const float* b  = (const float*)d_in[3];
    const int*   ng = (const int*)d_in[4];
    const int n_rows = in_sizes[0];

    float* out1       = (float*)d_out;
    float* out_interp = out1 + (size_t)n_rows * OUTD;

    const int n_tiles  = (n_rows + RPB - 1) / RPB;   // 15625
    const int n_blocks = 4096;                       // 16 one-wave blocks/CU
    density_kernel<<<dim3(n_blocks), dim3(64), 0, stream>>>(
        t, x, w, b, ng, out1, out_interp, n_rows, n_tiles, n_blocks);
}